// Round 10
// baseline (934.682 us; speedup 1.0000x reference)
//
#include <hip/hip_runtime.h>

// BendingEnergy: fused 19-point stencil + per-batch mean, LDS x-march v6.
// f: (4, 160, 160, 160, 3) f32, m = z*3+c fused contiguous axis (480/row).
// Block(256) = 16 y-rows x 16 m-tiles (8-wide). Register x-FIFO: each LDS row
// is read ONCE (at slab x+1) and carried in registers: center row depth-4
// (XP->C->XM->X2M), y+-1 rows depth-3 (DPP->YP->DMP). Only X2P (x+2) and
// y+-2 rows (x) are direct reads: 20 units/thread-step (was 30). Only slabs
// {x, x+1, x+2} are read -> 4-slot circular buffer (47.6 KB). STEPS=12 fully
// unrolled (12 % 4 == 0, 12 % 3 == 0) -> all FIFO indices compile-time;
// X0 == 2 (mod 4) -> all slot indices compile-time.

typedef float F4 __attribute__((ext_vector_type(4)));

#define DIM 160
#define SX (DIM * DIM * 3)          // 76800
#define SY (DIM * 3)                // 480
#define FSZ ((long long)DIM * SX)
#define TOT (4LL * FSZ)

#define ROWS 20                     // staged y rows per slab (16 out + 4 halo)
#define ROWU 37                     // 16B units per row (36 used + 1 pad)
#define USED_U (ROWS * ROWU)        // 740
#define SLICE_U 744                 // padded to mult of 8
#define SLICE_F (SLICE_U * 4)       // 2976 floats
#define SLOTS 4
#define STEPS 12
#define NSEG 13                     // 13 * 12 = 156
#define NMS 4                       // m segments (128 output floats each)
#define NYT 10                      // y tiles (16 rows each)
#define NBLK (4 * NSEG * NMS * NYT) // 2080
#define CPX (NBLK / 8)              // 260

#define CB(a, i) a[(i) >> 2][(i) & 3]

__global__ __launch_bounds__(256, 2) void be_kernel(const float* __restrict__ f,
                                                    float* __restrict__ out) {
    __shared__ float lds[SLICE_F * SLOTS];   // 47616 B
    const int tid = threadIdx.x;

    // bijective XCD chunking; same-XCD blocks share (b, xseg) slab volumes
    int lid = (blockIdx.x & 7) * CPX + (blockIdx.x >> 3);
    int p2 = lid / (NMS * NYT);
    int q2 = lid % (NMS * NYT);
    int b = p2 / NSEG, xseg = p2 % NSEG;
    int ms = q2 / NYT, yt = q2 % NYT;

    const int X0 = 2 + xseg * STEPS;         // X0 % 4 == 2 always
    const int gy0 = 16 * yt;                 // first staged global y row
    const int core = 4 + 128 * ms;           // first output m of this segment
    const int Gm = core - 8;                 // staged m start (16B-aligned)
    const long long bb = (long long)b * FSZ;
    const float* fbase = f + bb;
    const float* fend = f + (TOT - 4);

    const int t = tid >> 4;                  // m-tile 0..15
    const int yy = tid & 15;                 // y row within tile
    const int m0 = core + 8 * t;
    const int y = 2 + 16 * yt + yy;

    int jlo = 6 - m0; if (jlo < 0) jlo = 0;  // valid m in [6, 474)
    int jhi = 474 - m0; if (jhi > 8) jhi = 8;
    if (y >= DIM - 2) jhi = -1;              // y edge mask

    // unit of (center row, m0-8); every LDS access is slot-const + this + imm
    const int rc = (yy + 2) * ROWU + 2 * t;

    // stage chunk global offsets (fixed per thread)
    long long choff[3];
#pragma unroll
    for (int it = 0; it < 3; ++it) {
        int c = it * 256 + tid;
        int row = c / ROWU, col = c - row * ROWU;
        choff[it] = (long long)(gy0 + row) * SY + Gm + 4 * col;
    }
    const bool ch2ok = (512 + tid) < USED_U;

    auto stage = [&](int slab, int slot) {
        long long sb = (long long)slab * SX;
#pragma unroll
        for (int it = 0; it < 3; ++it) {
            if (it < 2 || ch2ok) {
                const float* gp = fbase + (sb + choff[it]);
                gp = gp < f ? f : gp;        // clamp buffer ends (masked data)
                gp = gp > fend ? fend : gp;
                __builtin_amdgcn_global_load_lds(
                    (const __attribute__((address_space(1))) unsigned int*)gp,
                    (__attribute__((address_space(3))) unsigned int*)
                        ((__attribute__((address_space(3))) float*)lds
                         + slot * SLICE_F + 4 * (it * 256 + tid)),
                    16, 0, 0);
            }
        }
    };

    auto LD = [&](int slot, int unit) -> F4 {
        return *reinterpret_cast<const F4*>(lds + slot * SLICE_F + 4 * unit);
    };

    // prologue: slabs X0-2..X0+1 into slots 0..3 (slot = (2+d)&3)
    stage(X0 - 2, 0); stage(X0 - 1, 1); stage(X0, 2); stage(X0 + 1, 3);
    __syncthreads();

    // FIFO register state
    F4 CF[4][6];                    // center row: [age ring][unit]
    F4 YPF[3][4], YMF[3][4];        // y+-1 rows: [age ring][unit]

    // seeds: entries that step 0 consumes at ages 1..3
#pragma unroll
    for (int i = 0; i < 6; ++i) CF[3][i] = LD(2, rc + i);            // slab X0   (C@0)
#pragma unroll
    for (int i = 1; i < 5; ++i) CF[2][i] = LD(1, rc + i);            // slab X0-1 (XM@0)
    CF[1][2] = LD(0, rc + 2); CF[1][3] = LD(0, rc + 3);              // slab X0-2 (X2M@0)
#pragma unroll
    for (int i = 0; i < 4; ++i) {
        YPF[2][i] = LD(2, rc + ROWU + 1 + i);                        // slab X0   (YP@0)
        YMF[2][i] = LD(2, rc - ROWU + 1 + i);
    }
    YPF[1][1] = LD(1, rc + ROWU + 2); YPF[1][2] = LD(1, rc + ROWU + 3);  // X0-1 (DMP@0)
    YMF[1][1] = LD(1, rc - ROWU + 2); YMF[1][2] = LD(1, rc - ROWU + 3);
    __syncthreads();                 // all seed reads done before slot 0 reuse

    stage(X0 + 2, 0);                // overwrites slot of X0-2 (consumed)
    __syncthreads();                 // landed before step 0 reads slab X0+2

    float e = 0.0f;                  // raw energy (x16 scale)

#pragma unroll
    for (int s = 0; s < STEPS; ++s) {
        const int x = X0 + s;
        if (s <= STEPS - 2) stage(x + 3, (s + 1) & 3);   // slot (2+s+3)&3

        const int sl0 = (2 + s) & 3;     // slab x
        const int sl1 = (3 + s) & 3;     // slab x+1
        const int sl2 = (s) & 3;         // slab x+2

        // FIFO fills from slab x+1 (read once, used over 3-4 steps)
        F4* cfA = CF[s & 3];
        F4* ypA = YPF[s % 3];
        F4* ymA = YMF[s % 3];
#pragma unroll
        for (int i = 0; i < 6; ++i) cfA[i] = LD(sl1, rc + i);
#pragma unroll
        for (int i = 0; i < 4; ++i) {
            ypA[i] = LD(sl1, rc + ROWU + 1 + i);
            ymA[i] = LD(sl1, rc - ROWU + 1 + i);
        }
        // direct reads
        F4 X2Pa[2], Y2Pa[2], Y2Ma[2];
        X2Pa[0] = LD(sl2, rc + 2);            X2Pa[1] = LD(sl2, rc + 3);
        Y2Pa[0] = LD(sl0, rc + 2 * ROWU + 2); Y2Pa[1] = LD(sl0, rc + 2 * ROWU + 3);
        Y2Ma[0] = LD(sl0, rc - 2 * ROWU + 2); Y2Ma[1] = LD(sl0, rc - 2 * ROWU + 3);

        const F4* cfC   = CF[(s + 3) & 3];    // slab x   (C, dzz)
        const F4* cfXM  = CF[(s + 2) & 3];    // slab x-1
        const F4* cfX2M = CF[(s + 1) & 3];    // slab x-2
        const F4* ypYP  = YPF[(s + 2) % 3];   // slab x
        const F4* ypDMP = YPF[(s + 1) % 3];   // slab x-1
        const F4* ymYM  = YMF[(s + 2) % 3];
        const F4* ymDMM = YMF[(s + 1) % 3];

#pragma unroll
        for (int j = 0; j < 8; ++j) {
            float ctr2 = 2.0f * CB(cfC, j + 8);
            float dxx = (CB(X2Pa, j) + CB(cfX2M, j + 8)) - ctr2;
            float dyy = (CB(Y2Pa, j) + CB(Y2Ma, j)) - ctr2;
            float dzz = (CB(cfC, j + 2) + CB(cfC, j + 14)) - ctr2;
            float dxy = (CB(ypA, j + 4) - CB(ypDMP, j + 4))
                      - (CB(ymA, j + 4) - CB(ymDMM, j + 4));
            float dxz = (CB(cfA, j + 11) - CB(cfXM, j + 11))
                      - (CB(cfA, j + 5) - CB(cfXM, j + 5));
            float dyz = (CB(ypYP, j + 7) - CB(ymYM, j + 7))
                      - (CB(ypYP, j + 1) - CB(ymYM, j + 1));
            float dd = dxx * dxx + dyy * dyy + dzz * dzz;
            float dc = dxy * dxy + dxz * dxz + dyz * dyz;
            float msk = (j >= jlo && j < jhi) ? 1.0f : 0.0f;
            e += msk * (dd + 2.0f * dc);
        }

        __syncthreads();   // drains stage vmcnt + orders slot reuse
    }

    // wave reduce -> block reduce -> one atomic per block
#pragma unroll
    for (int off = 32; off > 0; off >>= 1) e += __shfl_down(e, off, 64);

    __shared__ float ws[4];
    int lane = tid & 63;
    int wid = tid >> 6;
    if (lane == 0) ws[wid] = e;
    __syncthreads();
    if (tid == 0) {
        // 0.0625 = (0.25)^2 from the two central-difference factors
        const float inv_count = 0.0625f / (156.0f * 156.0f * 156.0f * 3.0f);
        atomicAdd(&out[b], (ws[0] + ws[1] + ws[2] + ws[3]) * inv_count);
    }
}

extern "C" void kernel_launch(void* const* d_in, const int* in_sizes, int n_in,
                              void* d_out, int out_size, void* d_ws, size_t ws_size,
                              hipStream_t stream) {
    const float* f = (const float*)d_in[0];
    float* out = (float*)d_out;

    hipMemsetAsync(d_out, 0, out_size * sizeof(float), stream);

    be_kernel<<<dim3(NBLK), dim3(256), 0, stream>>>(f, out);
}

// Round 11
// 92.588 us; speedup vs baseline: 10.0951x; 10.0951x over previous
//
#include <hip/hip_runtime.h>

// BendingEnergy: fused 19-point stencil + per-batch mean, LDS x-march v7.
// v6's dataflow (each LDS row read ONCE per x-march, carried in registers;
// 20 units/thread-step; 4-slot circular buffer) with v5's codegen discipline:
// flat 1-D F4 arrays, literal indices only, by-value shift rotation, rolled
// x-loop, no pointers into locals (round-10 scratch disaster = rule #20).
// Center row: read at slab x+1, serves XP -> C -> XM -> X2M (depth 4).
// y+-1 rows: read at slab x+1, serve DPP -> YP -> DMP (depth 3).
// Direct reads: X2P (x+2), Y2P/Y2M (x).

typedef float F4 __attribute__((ext_vector_type(4)));

#define DIM 160
#define SX (DIM * DIM * 3)          // 76800
#define SY (DIM * 3)                // 480
#define FSZ ((long long)DIM * SX)
#define TOT (4LL * FSZ)

#define ROWS 20                     // staged y rows per slab (16 out + 4 halo)
#define ROWU 37                     // 16B units per row (36 used + 1 pad)
#define USED_U (ROWS * ROWU)        // 740
#define SLICE_U 744                 // padded to mult of 8
#define SLICE_F (SLICE_U * 4)       // 2976 floats
#define SLOTS 4
#define STEPS 26
#define NSEG 6
#define NMS 4                       // m segments (128 output floats each)
#define NYT 10                      // y tiles (16 rows each)
#define NBLK (4 * NSEG * NMS * NYT) // 960
#define CPX (NBLK / 8)              // 120

#define CB(a, i) a[(i) >> 2][(i) & 3]

__global__ __launch_bounds__(256, 2) void be_kernel(const float* __restrict__ f,
                                                    float* __restrict__ out) {
    __shared__ float lds[SLICE_F * SLOTS];   // 47616 B
    const int tid = threadIdx.x;

    // bijective XCD chunking; same-XCD blocks share (b, xseg) slab volumes
    int lid = (blockIdx.x & 7) * CPX + (blockIdx.x >> 3);
    int p2i = lid / (NMS * NYT);
    int q2i = lid % (NMS * NYT);
    int b = p2i / NSEG, xseg = p2i % NSEG;
    int ms = q2i / NYT, yt = q2i % NYT;

    const int X0 = 2 + xseg * STEPS;
    const int gy0 = 16 * yt;                 // first staged global y row
    const int core = 4 + 128 * ms;           // first output m of this segment
    const int Gm = core - 8;                 // staged m start (16B-aligned)
    const long long bb = (long long)b * FSZ;
    const float* fbase = f + bb;
    const float* fend = f + (TOT - 4);

    const int t = tid >> 4;                  // m-tile 0..15
    const int yy = tid & 15;                 // y row within tile
    const int m0 = core + 8 * t;
    const int y = 2 + 16 * yt + yy;

    int jlo = 6 - m0; if (jlo < 0) jlo = 0;  // valid m in [6, 474)
    int jhi = 474 - m0; if (jhi > 8) jhi = 8;
    if (y >= DIM - 2) jhi = -1;              // y edge mask

    // unit of (center row, m0-8); every LDS access is slot-base + rc + imm
    const int rc = (yy + 2) * ROWU + 2 * t;

    // stage chunk global offsets (fixed per thread)
    long long choff[3];
#pragma unroll
    for (int it = 0; it < 3; ++it) {
        int c = it * 256 + tid;
        int row = c / ROWU, col = c - row * ROWU;
        choff[it] = (long long)(gy0 + row) * SY + Gm + 4 * col;
    }
    const bool ch2ok = (512 + tid) < USED_U;

    auto stage = [&](int slab, int slot) {
        long long sb = (long long)slab * SX;
#pragma unroll
        for (int it = 0; it < 3; ++it) {
            if (it < 2 || ch2ok) {
                const float* gp = fbase + (sb + choff[it]);
                gp = gp < f ? f : gp;        // clamp buffer ends (masked data)
                gp = gp > fend ? fend : gp;
                __builtin_amdgcn_global_load_lds(
                    (const __attribute__((address_space(1))) unsigned int*)gp,
                    (__attribute__((address_space(3))) unsigned int*)
                        ((__attribute__((address_space(3))) float*)lds
                         + slot * SLICE_F + 4 * (it * 256 + tid)),
                    16, 0, 0);
            }
        }
    };

    auto LD = [&](const float* base, int unit) -> F4 {
        return *reinterpret_cast<const F4*>(base + 4 * unit);
    };

    // prologue: slabs X0-2..X0+1 -> slots 0..3 (slab X0-2+k -> slot k&3)
    stage(X0 - 2, 0); stage(X0 - 1, 1); stage(X0, 2); stage(X0 + 1, 3);
    __syncthreads();

    // persistent shift-register state (flat arrays, literal indices only)
    F4 r1[6], r2[4], r3[2];          // center row: slabs x, x-1, x-2
    F4 p1[4], p2[2];                 // y+1 row:    slabs x, x-1
    F4 q1[4], q2[2];                 // y-1 row:    slabs x, x-1
    {
        const float* L2 = lds + 2 * SLICE_F;     // slab X0
        const float* L1 = lds + 1 * SLICE_F;     // slab X0-1
        const float* L0 = lds + 0 * SLICE_F;     // slab X0-2
#pragma unroll
        for (int i = 0; i < 6; ++i) r1[i] = LD(L2, rc + i);
#pragma unroll
        for (int i = 0; i < 4; ++i) r2[i] = LD(L1, rc + 1 + i);
        r3[0] = LD(L0, rc + 2); r3[1] = LD(L0, rc + 3);
#pragma unroll
        for (int i = 0; i < 4; ++i) {
            p1[i] = LD(L2, rc + ROWU + 1 + i);
            q1[i] = LD(L2, rc - ROWU + 1 + i);
        }
        p2[0] = LD(L1, rc + ROWU + 2); p2[1] = LD(L1, rc + ROWU + 3);
        q2[0] = LD(L1, rc - ROWU + 2); q2[1] = LD(L1, rc - ROWU + 3);
    }
    __syncthreads();                 // seeds done before slot 0 reuse
    stage(X0 + 2, 0);                // slab X0+2 -> slot 0 (over X0-2)
    __syncthreads();                 // landed before step 0 reads it

    float e = 0.0f;                  // raw energy (x16 scale)

    for (int s = 0; s < STEPS; ++s) {
        const int x = X0 + s;
        if (s <= STEPS - 2) stage(x + 3, (s + 1) & 3);   // over slab x-1 slot

        const float* Lx  = lds + ((s + 2) & 3) * SLICE_F;  // slab x
        const float* Lx1 = lds + ((s + 3) & 3) * SLICE_F;  // slab x+1
        const float* Lx2 = lds + ((s) & 3) * SLICE_F;      // slab x+2

        // fresh reads: 20 units
        F4 r0[6], p0[4], q0[4], X2Pa[2], Y2Pa[2], Y2Ma[2];
#pragma unroll
        for (int i = 0; i < 6; ++i) r0[i] = LD(Lx1, rc + i);
#pragma unroll
        for (int i = 0; i < 4; ++i) {
            p0[i] = LD(Lx1, rc + ROWU + 1 + i);
            q0[i] = LD(Lx1, rc - ROWU + 1 + i);
        }
        X2Pa[0] = LD(Lx2, rc + 2);            X2Pa[1] = LD(Lx2, rc + 3);
        Y2Pa[0] = LD(Lx, rc + 2 * ROWU + 2);  Y2Pa[1] = LD(Lx, rc + 2 * ROWU + 3);
        Y2Ma[0] = LD(Lx, rc - 2 * ROWU + 2);  Y2Ma[1] = LD(Lx, rc - 2 * ROWU + 3);

        // r1 = C (slab x, floats idx k = m0-8+k), r0 = XP (x+1), r2 = XM
        // (x-1, k = l+4), r3 = X2M (x-2, k = l+8); p0 = DPP, p1 = YP
        // (idx = m0-4+i), p2 = DMP (idx = l+4); q* = y-1 mirror.
#pragma unroll
        for (int j = 0; j < 8; ++j) {
            float ctr2 = 2.0f * CB(r1, j + 8);
            float dxx = (CB(X2Pa, j) + CB(r3, j)) - ctr2;
            float dyy = (CB(Y2Pa, j) + CB(Y2Ma, j)) - ctr2;
            float dzz = (CB(r1, j + 2) + CB(r1, j + 14)) - ctr2;
            float dxy = (CB(p0, j + 4) - CB(p2, j)) - (CB(q0, j + 4) - CB(q2, j));
            float dxz = (CB(r0, j + 11) - CB(r2, j + 7)) - (CB(r0, j + 5) - CB(r2, j + 1));
            float dyz = (CB(p1, j + 7) - CB(q1, j + 7)) - (CB(p1, j + 1) - CB(q1, j + 1));
            float dd = dxx * dxx + dyy * dyy + dzz * dzz;
            float dc = dxy * dxy + dxz * dxz + dyz * dyz;
            float msk = (j >= jlo && j < jhi) ? 1.0f : 0.0f;
            e += msk * (dd + 2.0f * dc);
        }

        // shift registers by value (oldest first; literal indices only)
        r3[0] = r2[1]; r3[1] = r2[2];
#pragma unroll
        for (int i = 0; i < 4; ++i) r2[i] = r1[i + 1];
#pragma unroll
        for (int i = 0; i < 6; ++i) r1[i] = r0[i];
        p2[0] = p1[1]; p2[1] = p1[2];
        q2[0] = q1[1]; q2[1] = q1[2];
#pragma unroll
        for (int i = 0; i < 4; ++i) { p1[i] = p0[i]; q1[i] = q0[i]; }

        __syncthreads();   // drains stage vmcnt + orders slot reuse
    }

    // wave reduce -> block reduce -> one atomic per block
#pragma unroll
    for (int off = 32; off > 0; off >>= 1) e += __shfl_down(e, off, 64);

    __shared__ float ws[4];
    int lane = tid & 63;
    int wid = tid >> 6;
    if (lane == 0) ws[wid] = e;
    __syncthreads();
    if (tid == 0) {
        // 0.0625 = (0.25)^2 from the two central-difference factors
        const float inv_count = 0.0625f / (156.0f * 156.0f * 156.0f * 3.0f);
        atomicAdd(&out[b], (ws[0] + ws[1] + ws[2] + ws[3]) * inv_count);
    }
}

extern "C" void kernel_launch(void* const* d_in, const int* in_sizes, int n_in,
                              void* d_out, int out_size, void* d_ws, size_t ws_size,
                              hipStream_t stream) {
    const float* f = (const float*)d_in[0];
    float* out = (float*)d_out;

    hipMemsetAsync(d_out, 0, out_size * sizeof(float), stream);

    be_kernel<<<dim3(NBLK), dim3(256), 0, stream>>>(f, out);
}